// Round 1
// baseline (797.554 us; speedup 1.0000x reference)
//
#include <hip/hip_runtime.h>
#include <math.h>

#define D_EMB 512
#define HD 64
#define BB 8
#define NN 2048
#define QT 64
#define KT 64

// ---------------- Projection: out[which][row][c] = sum_k X[row][k] * W[k][c]
// which: 0=Q(query_input), 1=K(key_input), 2=V(value_input); all use W_key.
// One wave per 1 row group of 4 rows per block (256 thr = 4 rows x 64 lanes).
__global__ __launch_bounds__(256)
void proj_kernel(const float* __restrict__ Xq,
                 const float* __restrict__ Xk,
                 const float* __restrict__ Xv,
                 const float* __restrict__ W,
                 float* __restrict__ out)
{
    const float* X = (blockIdx.y == 0) ? Xq : (blockIdx.y == 1 ? Xk : Xv);
    int row = blockIdx.x * 4 + (threadIdx.x >> 6);
    int c = threadIdx.x & 63;
    const float* xrow = X + (size_t)row * D_EMB;
    float acc = 0.f;
#pragma unroll 8
    for (int k = 0; k < D_EMB; ++k)
        acc = fmaf(xrow[k], W[k * HD + c], acc);
    out[((size_t)blockIdx.y * (BB * NN) + row) * HD + c] = acc;
}

// ---------------- Flash attention (fp32, online softmax), causal + padding.
// Block: 256 threads = 64 q-rows x 4 col-groups. Q row in registers.
__global__ __launch_bounds__(256)
void attn_kernel(const float* __restrict__ QKV,
                 const unsigned char* __restrict__ pad,   // [B][N], bytes (all 0)
                 const int* __restrict__ mflag,
                 float* __restrict__ out)
{
    const float* Q = QKV;
    const float* K = QKV + (size_t)(BB * NN) * HD;
    const float* V = QKV + (size_t)2 * (BB * NN) * HD;

    int b  = blockIdx.y;
    int qt = blockIdx.x;
    int q0 = qt * QT;
    int tid = threadIdx.x;
    int r  = tid >> 2;   // local q row 0..63
    int cg = tid & 3;    // column group 0..3
    bool causal = (mflag[0] != 0);
    int nkt = causal ? (qt + 1) : (NN / KT);

    __shared__ float sK[KT][HD + 4];   // stride 68: b128 reads conflict-free w/ kc=4j+cg
    __shared__ float sV[KT][HD];       // unpadded: aligned b128, 2-way (free)
    __shared__ float sP[QT][KT + 4];   // stride 68: 2-way on reads (free)

    // Q row -> registers (64 floats)
    float4 qreg[16];
    {
        const float4* qsrc = (const float4*)(Q + ((size_t)b * NN + q0 + r) * HD);
#pragma unroll
        for (int i = 0; i < 16; ++i) qreg[i] = qsrc[i];
    }

    float m_i = -INFINITY, l_i = 0.f;
    float o[16];
#pragma unroll
    for (int j = 0; j < 16; ++j) o[j] = 0.f;

    const float scale = 0.04419417382415922f;   // 1/sqrt(512)
    const unsigned char* padb = pad + (size_t)b * NN;

    for (int kt = 0; kt < nkt; ++kt) {
        int k0 = kt * KT;
        __syncthreads();   // protect sK/sV/sP from previous iteration's readers
        {
            const float* srcK = K + ((size_t)b * NN + k0) * HD;
            const float* srcV = V + ((size_t)b * NN + k0) * HD;
            for (int i = tid; i < KT * HD / 4; i += 256) {
                int rr = i >> 4;
                int cc = i & 15;
                ((float4*)&sK[rr][0])[cc] = ((const float4*)srcK)[i];
                ((float4*)&sV[rr][0])[cc] = ((const float4*)srcV)[i];
            }
        }
        __syncthreads();

        // S row chunk: this thread handles kc = 4j+cg, j=0..15
        float sv_[16];
#pragma unroll
        for (int j = 0; j < 16; ++j) {
            int kc = 4 * j + cg;
            float acc = 0.f;
            const float4* krow = (const float4*)&sK[kc][0];
#pragma unroll
            for (int d4 = 0; d4 < 16; ++d4) {
                float4 kv = krow[d4];
                float4 qv = qreg[d4];
                acc = fmaf(qv.x, kv.x, acc);
                acc = fmaf(qv.y, kv.y, acc);
                acc = fmaf(qv.z, kv.z, acc);
                acc = fmaf(qv.w, kv.w, acc);
            }
            acc *= scale;
            int kg = k0 + kc;
            if (padb[kg]) acc = -INFINITY;
            if (causal && kg > q0 + r) acc = -INFINITY;
            sv_[j] = acc;
        }

        // row max over 64 kc: 16 local + reduce over the 4 consecutive lanes
        float mt = sv_[0];
#pragma unroll
        for (int j = 1; j < 16; ++j) mt = fmaxf(mt, sv_[j]);
        mt = fmaxf(mt, __shfl_xor(mt, 1));
        mt = fmaxf(mt, __shfl_xor(mt, 2));
        float m_new = fmaxf(m_i, mt);

        float alpha = __expf(m_i - m_new);   // first tile: exp(-inf)=0
        float psum = 0.f;
#pragma unroll
        for (int j = 0; j < 16; ++j) {
            float p = __expf(sv_[j] - m_new);
            sv_[j] = p;
            psum += p;
        }
        psum += __shfl_xor(psum, 1);
        psum += __shfl_xor(psum, 2);
        l_i = l_i * alpha + psum;
        m_i = m_new;
#pragma unroll
        for (int j = 0; j < 16; ++j) o[j] *= alpha;

#pragma unroll
        for (int j = 0; j < 16; ++j) sP[r][4 * j + cg] = sv_[j];
        __syncthreads();

        // O[r][cg*16 .. cg*16+15] += P[r][:] @ V[:][cols]
#pragma unroll 4
        for (int k = 0; k < KT; ++k) {
            float p = sP[r][k];
            const float4* vrow = (const float4*)&sV[k][0];
            float4 v0 = vrow[cg * 4 + 0];
            float4 v1 = vrow[cg * 4 + 1];
            float4 v2 = vrow[cg * 4 + 2];
            float4 v3 = vrow[cg * 4 + 3];
            o[0]  = fmaf(p, v0.x, o[0]);  o[1]  = fmaf(p, v0.y, o[1]);
            o[2]  = fmaf(p, v0.z, o[2]);  o[3]  = fmaf(p, v0.w, o[3]);
            o[4]  = fmaf(p, v1.x, o[4]);  o[5]  = fmaf(p, v1.y, o[5]);
            o[6]  = fmaf(p, v1.z, o[6]);  o[7]  = fmaf(p, v1.w, o[7]);
            o[8]  = fmaf(p, v2.x, o[8]);  o[9]  = fmaf(p, v2.y, o[9]);
            o[10] = fmaf(p, v2.z, o[10]); o[11] = fmaf(p, v2.w, o[11]);
            o[12] = fmaf(p, v3.x, o[12]); o[13] = fmaf(p, v3.y, o[13]);
            o[14] = fmaf(p, v3.z, o[14]); o[15] = fmaf(p, v3.w, o[15]);
        }
    }

    float inv_l = 1.0f / l_i;
    float* orow = out + ((size_t)b * NN + q0 + r) * HD + cg * 16;
    float4* o4 = (float4*)orow;
    o4[0] = make_float4(o[0] * inv_l,  o[1] * inv_l,  o[2] * inv_l,  o[3] * inv_l);
    o4[1] = make_float4(o[4] * inv_l,  o[5] * inv_l,  o[6] * inv_l,  o[7] * inv_l);
    o4[2] = make_float4(o[8] * inv_l,  o[9] * inv_l,  o[10] * inv_l, o[11] * inv_l);
    o4[3] = make_float4(o[12] * inv_l, o[13] * inv_l, o[14] * inv_l, o[15] * inv_l);
}

extern "C" void kernel_launch(void* const* d_in, const int* in_sizes, int n_in,
                              void* d_out, int out_size, void* d_ws, size_t ws_size,
                              hipStream_t stream) {
    const float* key_in   = (const float*)d_in[0];
    const float* query_in = (const float*)d_in[1];
    const float* value_in = (const float*)d_in[2];
    const unsigned char* pad = (const unsigned char*)d_in[3];
    const int* mflag      = (const int*)d_in[4];
    const float* Wk       = (const float*)d_in[5];
    // d_in[6], d_in[7] (W_query, W_value) intentionally unused — reference uses W_key for all.

    float* qkv = (float*)d_ws;   // [3][B*N][64] fp32 = 12 MB

    proj_kernel<<<dim3(BB * NN / 4, 3), 256, 0, stream>>>(query_in, key_in, value_in, Wk, qkv);
    attn_kernel<<<dim3(NN / QT, BB), 256, 0, stream>>>(qkv, pad, mflag, (float*)d_out);
}

// Round 2
// 210.550 us; speedup vs baseline: 3.7880x; 3.7880x over previous
//
#include <hip/hip_runtime.h>
#include <math.h>

#define D_EMB 512
#define HD 64
#define BB 8
#define NN 2048
#define MROWS (BB*NN)   // 16384
#define KT 64
#define QT 64

typedef short short8 __attribute__((ext_vector_type(8)));
typedef float f32x4  __attribute__((ext_vector_type(4)));

// round-to-nearest-even f32 -> bf16 (bit pattern in a short)
__device__ __forceinline__ short f2bf(float x){
    unsigned u = __float_as_uint(x);
    unsigned r = (u + 0x7fffu + ((u >> 16) & 1u)) >> 16;
    return (short)r;
}

// ---------------- Wt[n][k] (bf16) <- W[k][n] (f32). Tiny one-shot kernel.
__global__ __launch_bounds__(256)
void wt_kernel(const float* __restrict__ W, short* __restrict__ Wt){
    for (int idx = blockIdx.x * 256 + threadIdx.x; idx < D_EMB*HD; idx += 8*256){
        int k = idx >> 6, n = idx & 63;
        Wt[n*D_EMB + k] = f2bf(W[idx]);
    }
}

// ---------------- Projection via MFMA: out[m][c] = X[m][:] @ W[:][c], bf16 out.
// M = 3*16384 rows concatenated [Q;K;V]. Per wave: 32 rows x 64 cols.
// A-frag: X[m=lane&15][k=quad*8+j] (2 float4 global loads + cvt).
// B-frag: Wt[n=lane&15][k..] contiguous 16B global load (L1/L2 resident).
__global__ __launch_bounds__(256)
void proj_kernel(const float* __restrict__ Xq, const float* __restrict__ Xk,
                 const float* __restrict__ Xv, const short* __restrict__ Wt,
                 short* __restrict__ out)
{
    const int lane = threadIdx.x & 63;
    const int lc = lane & 15, quad = lane >> 4;
    const int wid = blockIdx.x * 4 + (threadIdx.x >> 6);
    const int m0 = wid * 32;                 // 384 blocks * 4 waves * 32 rows = 49152
    const int tensor = m0 >> 14;             // /16384 (no straddle: 32 | 16384)
    const int rloc = m0 & (MROWS - 1);
    const float* X = (tensor == 0) ? Xq : (tensor == 1 ? Xk : Xv);

    f32x4 acc[2][4];
    for (int mt = 0; mt < 2; ++mt)
        for (int t = 0; t < 4; ++t)
            for (int r = 0; r < 4; ++r) acc[mt][t][r] = 0.f;

    for (int c16 = 0; c16 < 16; ++c16){
        const int k0 = c16 * 32;
        short8 a[2];
#pragma unroll
        for (int mt = 0; mt < 2; ++mt){
            const float* xr = X + (size_t)(rloc + mt*16 + lc) * D_EMB + k0 + quad*8;
            float4 f0 = *(const float4*)xr;
            float4 f1 = *(const float4*)(xr + 4);
            short8 av;
            av[0]=f2bf(f0.x); av[1]=f2bf(f0.y); av[2]=f2bf(f0.z); av[3]=f2bf(f0.w);
            av[4]=f2bf(f1.x); av[5]=f2bf(f1.y); av[6]=f2bf(f1.z); av[7]=f2bf(f1.w);
            a[mt] = av;
        }
#pragma unroll
        for (int t = 0; t < 4; ++t){
            short8 bf = *(const short8*)(Wt + (size_t)(t*16 + lc)*D_EMB + k0 + quad*8);
            acc[0][t] = __builtin_amdgcn_mfma_f32_16x16x32_bf16(a[0], bf, acc[0][t], 0,0,0);
            acc[1][t] = __builtin_amdgcn_mfma_f32_16x16x32_bf16(a[1], bf, acc[1][t], 0,0,0);
        }
    }
    // D layout: col = lane&15, row = quad*4 + r
#pragma unroll
    for (int mt = 0; mt < 2; ++mt)
#pragma unroll
        for (int t = 0; t < 4; ++t)
#pragma unroll
            for (int r = 0; r < 4; ++r)
                out[(size_t)(m0 + mt*16 + quad*4 + r)*HD + t*16 + lc] = f2bf(acc[mt][t][r]);
}

// ---------------- Flash attention, bf16 MFMA, online softmax.
// Block: 256 thr = 4 waves; wave owns 16 q rows; QT=64 rows/block, KT=64.
__global__ __launch_bounds__(256)
void attn_kernel(const short* __restrict__ Qb, const short* __restrict__ Kb,
                 const short* __restrict__ Vb, const unsigned char* __restrict__ pad,
                 const int* __restrict__ mflag, float* __restrict__ out)
{
    __shared__ short sK [KT][72];   // [k][d], stride 72 -> 2-way conflicts only
    __shared__ short sVt[HD][72];   // [d][k] (transposed at staging)
    __shared__ short sP [QT][72];   // [q][k], wave-private rows -> no extra barrier

    const int tid = threadIdx.x;
    const int lane = tid & 63;
    const int lc = lane & 15, quad = lane >> 4;
    const int w = tid >> 6;
    const int b = blockIdx.y;
    const int qt = blockIdx.x;
    const int q0 = qt * QT;
    const bool causal = (mflag[0] != 0);
    const int nkt = causal ? (qt + 1) : (NN / KT);
    const float scale = 0.04419417382415922f;  // 1/sqrt(512)
    const unsigned char* padb = pad + (size_t)b * NN;
    const int qrow_my = q0 + w*16 + quad*4;    // + r

    // Q fragments: 16 rows/wave, K-dim 64 = 2 chunks of 32
    short8 qf[2];
    {
        const short* qrow = Qb + ((size_t)b*NN + q0 + w*16 + lc) * HD;
        qf[0] = *(const short8*)(qrow + quad*8);
        qf[1] = *(const short8*)(qrow + 32 + quad*8);
    }

    f32x4 o[4];
    float m_i[4], l_i[4];
    for (int t = 0; t < 4; ++t) for (int r = 0; r < 4; ++r) o[t][r] = 0.f;
    for (int r = 0; r < 4; ++r){ m_i[r] = -INFINITY; l_i[r] = 0.f; }

    for (int kt = 0; kt < nkt; ++kt){
        const int k0 = kt * KT;
        __syncthreads();                       // prev tile's readers done
        {   // stage K tile: 4 threads/row, 2x int4 each
            int r = tid >> 2, seg = tid & 3;
            const int4* src = (const int4*)(Kb + ((size_t)b*NN + k0 + r)*HD);
            int4 v0 = src[seg*2], v1 = src[seg*2 + 1];
            int4* dst = (int4*)&sK[r][0];
            dst[seg*2] = v0; dst[seg*2 + 1] = v1;
        }
        {   // stage V transposed: thread = (rowpair p, colblock cb); packed b32 writes
            int p = tid & 31, cb = tid >> 5;
            const short* v0p = Vb + ((size_t)b*NN + k0 + 2*p)*HD + cb*8;
            short8 a0 = *(const short8*)v0p;
            short8 a1 = *(const short8*)(v0p + HD);
#pragma unroll
            for (int j = 0; j < 8; ++j){
                unsigned pk = (unsigned short)a0[j] | (((unsigned)(unsigned short)a1[j]) << 16);
                *(unsigned*)&sVt[cb*8 + j][2*p] = pk;
            }
        }
        __syncthreads();

        // S = Q K^T  (A=Q, B=K^T: B[d][kcol] -> sK[kcol][d] rows, 16B reads)
        f32x4 s[4];
        for (int t = 0; t < 4; ++t) for (int r = 0; r < 4; ++r) s[t][r] = 0.f;
#pragma unroll
        for (int t = 0; t < 4; ++t){
            short8 kf0 = *(const short8*)&sK[t*16 + lc][quad*8];
            short8 kf1 = *(const short8*)&sK[t*16 + lc][32 + quad*8];
            s[t] = __builtin_amdgcn_mfma_f32_16x16x32_bf16(qf[0], kf0, s[t], 0,0,0);
            s[t] = __builtin_amdgcn_mfma_f32_16x16x32_bf16(qf[1], kf1, s[t], 0,0,0);
        }

        // scale + padding + causal (diagonal tile only)
        const bool diag = causal && (kt == qt);
        unsigned char pb[4];
#pragma unroll
        for (int t = 0; t < 4; ++t) pb[t] = padb[k0 + t*16 + lc];
#pragma unroll
        for (int t = 0; t < 4; ++t){
            const int kg = k0 + t*16 + lc;
#pragma unroll
            for (int r = 0; r < 4; ++r){
                float v = s[t][r] * scale;
                if (pb[t]) v = -INFINITY;
                if (diag && kg > qrow_my + r) v = -INFINITY;
                s[t][r] = v;
            }
        }

        // online softmax; row r lives in this quad's 16 lanes -> shfl_xor 1,2,4,8
        float alpha[4];
#pragma unroll
        for (int r = 0; r < 4; ++r){
            float tm = fmaxf(fmaxf(s[0][r], s[1][r]), fmaxf(s[2][r], s[3][r]));
            tm = fmaxf(tm, __shfl_xor(tm, 1));
            tm = fmaxf(tm, __shfl_xor(tm, 2));
            tm = fmaxf(tm, __shfl_xor(tm, 4));
            tm = fmaxf(tm, __shfl_xor(tm, 8));
            float mn = fmaxf(m_i[r], tm);
            alpha[r] = __expf(m_i[r] - mn);
            m_i[r] = mn;
        }
#pragma unroll
        for (int r = 0; r < 4; ++r){
            float acc = 0.f;
#pragma unroll
            for (int t = 0; t < 4; ++t){
                float p = __expf(s[t][r] - m_i[r]);
                acc += p;
                sP[w*16 + quad*4 + r][t*16 + lc] = f2bf(p);
            }
            acc += __shfl_xor(acc, 1); acc += __shfl_xor(acc, 2);
            acc += __shfl_xor(acc, 4); acc += __shfl_xor(acc, 8);
            l_i[r] = l_i[r]*alpha[r] + acc;
#pragma unroll
            for (int t = 0; t < 4; ++t) o[t][r] *= alpha[r];
        }

        // O += P V  (A=P from sP in A-layout; B=V: B[k][d] -> sVt[d][k] rows)
        short8 pf0 = *(const short8*)&sP[w*16 + lc][quad*8];
        short8 pf1 = *(const short8*)&sP[w*16 + lc][32 + quad*8];
#pragma unroll
        for (int t = 0; t < 4; ++t){
            short8 vf0 = *(const short8*)&sVt[t*16 + lc][quad*8];
            short8 vf1 = *(const short8*)&sVt[t*16 + lc][32 + quad*8];
            o[t] = __builtin_amdgcn_mfma_f32_16x16x32_bf16(pf0, vf0, o[t], 0,0,0);
            o[t] = __builtin_amdgcn_mfma_f32_16x16x32_bf16(pf1, vf1, o[t], 0,0,0);
        }
    }

#pragma unroll
    for (int r = 0; r < 4; ++r){
        float inv = 1.f / l_i[r];
        float* orow = out + ((size_t)b*NN + q0 + w*16 + quad*4 + r)*HD + lc;
#pragma unroll
        for (int t = 0; t < 4; ++t) orow[t*16] = o[t][r] * inv;
    }
}

extern "C" void kernel_launch(void* const* d_in, const int* in_sizes, int n_in,
                              void* d_out, int out_size, void* d_ws, size_t ws_size,
                              hipStream_t stream) {
    const float* key_in   = (const float*)d_in[0];
    const float* query_in = (const float*)d_in[1];
    const float* value_in = (const float*)d_in[2];
    const unsigned char* pad = (const unsigned char*)d_in[3];
    const int* mflag      = (const int*)d_in[4];
    const float* Wk       = (const float*)d_in[5];
    // d_in[6], d_in[7] (W_query, W_value) unused — reference uses W_key for all three.

    short* Qb = (short*)d_ws;                 // [16384][64] bf16
    short* Kb = Qb + (size_t)MROWS*HD;
    short* Vb = Kb + (size_t)MROWS*HD;
    short* Wt = Vb + (size_t)MROWS*HD;        // [64][512] bf16

    wt_kernel<<<8, 256, 0, stream>>>(Wk, Wt);
    proj_kernel<<<384, 256, 0, stream>>>(query_in, key_in, value_in, Wt, Qb);
    attn_kernel<<<dim3(NN/QT, BB), 256, 0, stream>>>(Qb, Kb, Vb, pad, mflag, (float*)d_out);
}